// Round 4
// baseline (398.950 us; speedup 1.0000x reference)
//
#include <hip/hip_runtime.h>
#include <hip/hip_cooperative_groups.h>

namespace cg = cooperative_groups;

// out[r*64+ch] = b[ch] + sum_{edges (r,c)} W[ch][c],  r normalized by row.min().
// N = 100000, C = 64, E = 3.2M.
//
// R15: R14 with the compile fix — __builtin_nontemporal_load requires native
//  vector types, not HIP_vector_type classes; use ext_vector_type typedefs.
// R14: single cooperative kernel (transpose+init | part | bgather separated by
//  grid.sync) -> kills ~40-80us of launch gaps (R12/R13 budget analysis: hot
//  kernels never summed to dur_us). Bucketing by LOW bits (k = r&511, local
//  row = r>>9): exactly 512 balanced buckets = co-resident grid, 1:1
//  block<->bucket in phase 2 (scan work E, no quantization tail), and part
//  arrivals/bucket/block ~12 -> single end-of-scan flush sweep of ~48B runs
//  (R13 lesson: 4-record flushes at nbkt=1563 caused 4x write amplification,
//  WRITE_SIZE 59MB, part 99us). SLOTS=30 covers mean+5sigma; spill paths kept.
//  Phase-2 dword/half-wave gather loop kept verbatim (proven R12/R13).
//  Lessons kept: no shfl-broadcast-per-record accum (R3/R7); no same-line
//  global atomics (R5 ~670us); independent gather loads (R6/R9).
// ws: flags | Wtb[(N+1)*64 bf16] | gtail[512*16] | ovf | recs[512*segcap]

#define OVF_MAX (1 << 19)
#define NBKT 512
#define BSH 9            // bucket = r & 511, local row = r >> 9
#define SLOTS 30
#define GT_STRIDE 16
#define SL 56            // LDS col-list slots per row
#define LROWS_MAX 196    // max local rows: ceil(100352/512)
#define SMEM_U32 15888   // max(512*30+512+16, 196*56+196, 2*64*65) uints

typedef unsigned int uint2_ev __attribute__((ext_vector_type(2)));
typedef unsigned int uint4_ev __attribute__((ext_vector_type(4)));

__device__ __forceinline__ float bf16u_to_f(unsigned short u) {
    union { unsigned int i; float f; } x; x.i = ((unsigned int)u) << 16; return x.f;
}
__device__ __forceinline__ float bflo(unsigned int u) {
    union { unsigned int i; float f; } x; x.i = u << 16; return x.f;
}
__device__ __forceinline__ float bfhi(unsigned int u) {
    union { unsigned int i; float f; } x; x.i = u & 0xFFFF0000u; return x.f;
}

__global__ __launch_bounds__(1024, 8) void LINK_fused_kernel(
    const unsigned int* __restrict__ words, int E, int N,
    const float* __restrict__ W, unsigned short* __restrict__ Wtb,
    int segcap, int* __restrict__ gtail, unsigned int* __restrict__ recs,
    int* __restrict__ ovf, int* __restrict__ flags,
    const float* __restrict__ bias, float* __restrict__ out) {
    __shared__ unsigned int smem[SMEM_U32];
    cg::grid_group grid = cg::this_grid();
    int tid = threadIdx.x;
    int lane = tid & 63, wid = tid >> 6;

    // ---- Phase 0: block 0 does init + dtype detect; all blocks transpose ----
    if (blockIdx.x == 0) {
        for (int k = tid; k < NBKT; k += 1024) gtail[k * GT_STRIDE] = 0;
        long long twoE = 2LL * E;
        unsigned int oddOr = 0u;
        int nscan = (int)(twoE < 8192 ? twoE : 8192);
        for (int i = tid; i < nscan; i += 1024) {
            if (i & 1) oddOr |= words[i];
            long long j = twoE - 1 - i;
            if (j >= nscan && (j & 1)) oddOr |= words[j];
        }
        for (int off = 32; off > 0; off >>= 1)
            oddOr |= (unsigned int)__shfl_down((int)oddOr, off, 64);
        if (lane == 0) smem[wid] = oddOr;
        __syncthreads();
        if (tid == 0) {
            unsigned int o = 0;
            for (int i = 0; i < 16; ++i) o |= smem[i];
            flags[0] = o ? 1 : 0;    // 1 = int32 layout
            flags[1] = 0x7f7f7f7f;   // rmin "infinity"
            flags[8] = 0;            // ovf count
        }
        __syncthreads();
    }
    {   // W [64][N] f32 -> Wtb [N+1][64] bf16 (RNE); row N = zeros (sentinel).
        float* tiles = (float*)smem;          // 2 x [64][65] f32
        int T = (N + 64) >> 6;                // ceil((N+1)/64) tiles
        int grp = tid >> 9;                   // 0..1
        int lt = tid & 511;
        int lx = lt & 63, ly = lt >> 6;       // ly in [0,8)
        float* mytile = tiles + grp * 4160;
        for (int t0 = blockIdx.x * 2; t0 < T; t0 += gridDim.x * 2) {
            int t = t0 + grp;
            __syncthreads();
            if (t < T) {
                int n0 = t << 6;
#pragma unroll
                for (int it = 0; it < 8; ++it) {
                    int ch = ly + (it << 3);
                    float v = 0.0f;
                    if (n0 + lx < N) v = W[(size_t)ch * N + (n0 + lx)];
                    mytile[lx * 65 + ch] = v;
                }
            }
            __syncthreads();
            if (t < T) {
                int n0 = t << 6;
#pragma unroll
                for (int it = 0; it < 8; ++it) {
                    int nn = ly + (it << 3);
                    if (n0 + nn <= N) {
                        union { float f; unsigned int i; } x; x.f = mytile[nn * 65 + lx];
                        unsigned int u = x.i;
                        unsigned int r = (u + 0x7fffu + ((u >> 16) & 1u)) >> 16;  // RNE
                        Wtb[((size_t)(n0 + nn) << 6) + lx] = (unsigned short)r;
                    }
                }
            }
        }
    }
    __threadfence();
    grid.sync();

    // ---- Phase 1: partition edges into 512 interleaved buckets ----
    {
        unsigned int* lstage = smem;                       // 512*30
        int* lcnt = (int*)(smem + NBKT * SLOTS);           // 512
        int* sred = (int*)(smem + NBKT * SLOTS + NBKT);    // 16
        for (int k = tid; k < NBKT; k += 1024) lcnt[k] = 0;
        __syncthreads();
        int isInt32 = flags[0];
        int mnr = 0x7f7f7f7f;
        long long P = ((long long)E + 1) >> 1;             // edge pairs
        long long stride = (long long)gridDim.x * 1024;
        for (long long p = (long long)blockIdx.x * 1024 + tid; p < P; p += stride) {
            long long e0 = p << 1;
            int r0, c0, r1 = 0, c1 = 0;
            bool has1 = (e0 + 1 < E);
            if (isInt32) {
                if (has1) {
                    uint2_ev rr = __builtin_nontemporal_load((const uint2_ev*)(words + e0));
                    uint2_ev cc = __builtin_nontemporal_load((const uint2_ev*)(words + E + e0));
                    r0 = (int)rr.x; r1 = (int)rr.y; c0 = (int)cc.x; c1 = (int)cc.y;
                } else {
                    r0 = (int)words[e0]; c0 = (int)words[E + e0];
                }
            } else {
                if (has1) {
                    uint4_ev rr = __builtin_nontemporal_load((const uint4_ev*)(words + (e0 << 1)));
                    uint4_ev cc = __builtin_nontemporal_load((const uint4_ev*)(words + 2LL * E + (e0 << 1)));
                    r0 = (int)rr.x; r1 = (int)rr.z; c0 = (int)cc.x; c1 = (int)cc.z;
                } else {
                    r0 = (int)words[e0 << 1]; c0 = (int)words[2LL * E + (e0 << 1)];
                }
            }
#pragma unroll
            for (int u = 0; u < 2; ++u) {
                if (u && !has1) break;
                int r = u ? r1 : r0, c = u ? c1 : c0;
                mnr = min(mnr, r);
                if ((unsigned)r < (unsigned)N && (unsigned)c < (unsigned)N) {
                    int k = r & (NBKT - 1);
                    unsigned int rec = ((unsigned int)(r >> BSH) << 17) | (unsigned int)c;
                    int pos = atomicAdd(&lcnt[k], 1);
                    if (pos < SLOTS) {
                        lstage[k * SLOTS + pos] = rec;
                    } else {  // rare overflow of staging: direct global append
                        int g = atomicAdd(&gtail[k * GT_STRIDE], 1);
                        if (g < segcap) recs[(size_t)k * segcap + g] = rec;
                        else {
                            int oi = atomicAdd(&flags[8], 1);
                            if (oi < OVF_MAX) { ovf[2 * oi] = r; ovf[2 * oi + 1] = c; }
                        }
                    }
                }
            }
        }
        __syncthreads();
        // single flush sweep: ~12-rec (48B) coalesced runs per bucket
        for (int k = wid; k < NBKT; k += 16) {
            int cnt = lcnt[k]; if (cnt > SLOTS) cnt = SLOTS;
            if (cnt > 0) {
                int g = 0;
                if (lane == 0) g = atomicAdd(&gtail[k * GT_STRIDE], cnt);
                g = __shfl(g, 0);
                if (lane < cnt) {
                    int gg = g + lane;
                    unsigned int rec = lstage[k * SLOTS + lane];
                    if (gg < segcap) recs[(size_t)k * segcap + gg] = rec;
                    else {
                        int oi = atomicAdd(&flags[8], 1);
                        if (oi < OVF_MAX) {
                            ovf[2 * oi] = (int)((rec >> 17) << BSH) | k;
                            ovf[2 * oi + 1] = (int)(rec & 0x1FFFF);
                        }
                    }
                }
            }
        }
        for (int off = 32; off > 0; off >>= 1) mnr = min(mnr, __shfl_down(mnr, off, 64));
        if (lane == 0) sred[wid] = mnr;
        __syncthreads();
        if (tid == 0) {
            int m = sred[0];
            for (int i = 1; i < 16; ++i) m = min(m, sred[i]);
            atomicMin(&flags[1], m);
        }
    }
    __threadfence();
    grid.sync();

    // ---- Phase 2: per-bucket gather (block b <-> bucket b) ----
    {
        int* lcols = (int*)smem;                    // LROWS_MAX*SL
        int* lcnt2 = (int*)smem + LROWS_MAX * SL;   // LROWS_MAX
        int nloc = (N + NBKT - 1) >> BSH;
        int half = lane >> 5, ln = lane & 31;
        const unsigned int* __restrict__ W32 = (const unsigned int*)Wtb;
        float bv = bias[(ln << 1) + half];
        int rmin = flags[1];
        for (int b = blockIdx.x; b < NBKT; b += gridDim.x) {
            __syncthreads();
            for (int k = tid; k < nloc; k += 1024) lcnt2[k] = 0;
            __syncthreads();
            int len = gtail[b * GT_STRIDE]; if (len > segcap) len = segcap;
            const unsigned int* rp = recs + (size_t)b * segcap;
            for (int i = tid; i < len; i += 1024) {
                unsigned int rec = rp[i];
                int lr = (int)(rec >> 17);
                int c = (int)(rec & 0x1FFFF);
                int pos = atomicAdd(&lcnt2[lr], 1);
                if (pos < SL) {
                    lcols[lr * SL + pos] = c;
                } else {  // astronomically rare: defer to global ovf cleanup
                    int oi = atomicAdd(&flags[8], 1);
                    if (oi < OVF_MAX) { ovf[2 * oi] = (lr << BSH) | b; ovf[2 * oi + 1] = c; }
                }
            }
            __syncthreads();
            // Pad odd-count rows to even with sentinel col N (Wtb row N == 0).
            if (tid < nloc) {
                int c0 = lcnt2[tid]; if (c0 > SL) c0 = SL;
                if (c0 & 1) { lcols[tid * SL + c0] = N; ++c0; }
                lcnt2[tid] = c0;
            }
            __syncthreads();
            for (int lr = wid; lr < nloc; lr += 16) {
                int cnt = lcnt2[lr];         // even, <= SL
                int base = lr * SL;
                float aL = 0.0f, aH = 0.0f;
                int j = 0;
                for (; j + 16 <= cnt; j += 16) {   // 16 recs: 8 dword loads/half
                    int4 q0 = *(const int4*)&lcols[base + j + (half << 2)];
                    int4 q1 = *(const int4*)&lcols[base + j + 8 + (half << 2)];
                    unsigned int u0 = W32[(((unsigned)q0.x) << 5) | ln];
                    unsigned int u1 = W32[(((unsigned)q0.y) << 5) | ln];
                    unsigned int u2 = W32[(((unsigned)q0.z) << 5) | ln];
                    unsigned int u3 = W32[(((unsigned)q0.w) << 5) | ln];
                    unsigned int u4 = W32[(((unsigned)q1.x) << 5) | ln];
                    unsigned int u5 = W32[(((unsigned)q1.y) << 5) | ln];
                    unsigned int u6 = W32[(((unsigned)q1.z) << 5) | ln];
                    unsigned int u7 = W32[(((unsigned)q1.w) << 5) | ln];
                    float l0 = (bflo(u0) + bflo(u1)) + (bflo(u2) + bflo(u3));
                    float l1 = (bflo(u4) + bflo(u5)) + (bflo(u6) + bflo(u7));
                    float h0 = (bfhi(u0) + bfhi(u1)) + (bfhi(u2) + bfhi(u3));
                    float h1 = (bfhi(u4) + bfhi(u5)) + (bfhi(u6) + bfhi(u7));
                    aL += l0 + l1;
                    aH += h0 + h1;
                }
                for (; j + 8 <= cnt; j += 8) {
                    int4 q = *(const int4*)&lcols[base + j + (half << 2)];
                    unsigned int u0 = W32[(((unsigned)q.x) << 5) | ln];
                    unsigned int u1 = W32[(((unsigned)q.y) << 5) | ln];
                    unsigned int u2 = W32[(((unsigned)q.z) << 5) | ln];
                    unsigned int u3 = W32[(((unsigned)q.w) << 5) | ln];
                    aL += (bflo(u0) + bflo(u1)) + (bflo(u2) + bflo(u3));
                    aH += (bfhi(u0) + bfhi(u1)) + (bfhi(u2) + bfhi(u3));
                }
                for (; j + 4 <= cnt; j += 4) {
                    int2 q = *(const int2*)&lcols[base + j + (half << 1)];
                    unsigned int u0 = W32[(((unsigned)q.x) << 5) | ln];
                    unsigned int u1 = W32[(((unsigned)q.y) << 5) | ln];
                    aL += bflo(u0) + bflo(u1);
                    aH += bfhi(u0) + bfhi(u1);
                }
                for (; j + 2 <= cnt; j += 2) {
                    int c = lcols[base + j + half];
                    unsigned int u = W32[(((unsigned)c) << 5) | ln];
                    aL += bflo(u);
                    aH += bfhi(u);
                }
                aL += __shfl_xor(aL, 32, 64);
                aH += __shfl_xor(aH, 32, 64);
                int orow = (lr << BSH) + b - rmin;
                if ((unsigned)orow < (unsigned)N)
                    out[((size_t)orow << 6) + (ln << 1) + half] = (half ? aH : aL) + bv;
            }
        }
    }
}

// Bias for out rows above the bucketed range (rmin large; usually no-op) +
// ovf cleanup (expected zero). Row regions are disjoint -> one kernel.
__global__ void LINK_tail_kernel(float* __restrict__ out, const float* __restrict__ bias,
                                 const int* __restrict__ flags, const int* __restrict__ ovf,
                                 const unsigned short* __restrict__ Wtb, int N) {
    int rmin = flags[1];
    int nloc = (N + NBKT - 1) >> BSH;
    long long start = (long long)nloc * NBKT - (long long)rmin;
    if (start < 0) start = 0;
    if (start < N) {
        long long total = ((long long)N - start) * 64;
        long long base = start * 64;
        long long i0 = (long long)blockIdx.x * blockDim.x + threadIdx.x;
        long long stride = (long long)gridDim.x * blockDim.x;
        for (long long i = i0; i < total; i += stride) out[base + i] = bias[(int)(i & 63)];
    }
    int cnt = flags[8]; if (cnt > OVF_MAX) cnt = OVF_MAX;
    if (cnt == 0) return;
    int g = blockIdx.x * blockDim.x + threadIdx.x;
    int w = g >> 6, lane = g & 63;
    int nw = (gridDim.x * blockDim.x) >> 6;
    for (int i = w; i < cnt; i += nw) {
        int r = ovf[2 * i] - rmin;
        int c = ovf[2 * i + 1];
        if ((unsigned)r >= (unsigned)N || (unsigned)c >= (unsigned)N) continue;
        atomicAdd(&out[((size_t)r << 6) + lane], bf16u_to_f(Wtb[((size_t)c << 6) + lane]));
    }
}

// ---- Fallback path (unexpected shapes/ws or coop-launch failure) ----
__global__ void LINK_initout_kernel(float* __restrict__ out, const float* __restrict__ b,
                                    int total, int* __restrict__ flags) {
    int i = blockIdx.x * blockDim.x + threadIdx.x;
    if (i == 0) { flags[0] = 0; flags[1] = 0x7fffffff; flags[2] = 0x7fffffff; }
    if (i < total) out[i] = b[i & 63];
}

__global__ __launch_bounds__(256) void LINK_analyze_kernel(
    const unsigned int* __restrict__ words, int E, int* __restrict__ flags) {
    const uint4* __restrict__ w4 = (const uint4*)words;
    int tid = blockIdx.x * blockDim.x + threadIdx.x;
    int nth = gridDim.x * blockDim.x;
    int n1 = E >> 2;
    long long twoE = 2LL * E;
    int n2 = (int)(twoE >> 2);
    unsigned int oddOr = 0u;
    int mn32 = 0x7fffffff, mn64 = 0x7fffffff;
    for (int i = tid; i < n2; i += nth) {
        uint4 w = w4[i];
        oddOr |= (w.y | w.w);
        mn64 = min(mn64, min((int)w.x, (int)w.z));
        if (i < n1)
            mn32 = min(mn32, min(min((int)w.x, (int)w.y), min((int)w.z, (int)w.w)));
    }
    for (long long i = ((long long)n1 << 2) + tid; i < E; i += nth)
        mn32 = min(mn32, (int)words[i]);
    for (long long i = ((long long)n2 << 2) + tid; i < twoE; i += nth) {
        unsigned int w = words[i];
        if (i & 1) oddOr |= w; else mn64 = min(mn64, (int)w);
    }
    for (int off = 32; off > 0; off >>= 1) {
        oddOr |= (unsigned int)__shfl_down((int)oddOr, off, 64);
        mn32 = min(mn32, __shfl_down(mn32, off, 64));
        mn64 = min(mn64, __shfl_down(mn64, off, 64));
    }
    __shared__ int s_or[4], s_m32[4], s_m64[4];
    int wid = threadIdx.x >> 6;
    if ((threadIdx.x & 63) == 0) { s_or[wid] = (int)oddOr; s_m32[wid] = mn32; s_m64[wid] = mn64; }
    __syncthreads();
    if (threadIdx.x == 0) {
        int o = s_or[0] | s_or[1] | s_or[2] | s_or[3];
        int a = min(min(s_m32[0], s_m32[1]), min(s_m32[2], s_m32[3]));
        int d = min(min(s_m64[0], s_m64[1]), min(s_m64[2], s_m64[3]));
        if (o) atomicOr(&flags[0], 1);
        atomicMin(&flags[1], a);
        atomicMin(&flags[2], d);
    }
}

__global__ void LINK_scatter_kernel(const unsigned int* __restrict__ words, int E,
                                    const float* __restrict__ W,
                                    float* __restrict__ out,
                                    const int* __restrict__ flags, int N) {
    long long g = (long long)blockIdx.x * blockDim.x + threadIdx.x;
    int e = (int)(g >> 6);
    if (e >= E) return;
    int ch = (int)(g & 63);
    int r, c, rmin;
    if (flags[0]) { r = (int)words[e]; c = (int)words[E + e]; rmin = flags[1]; }
    else { r = (int)words[2LL * e]; c = (int)words[2LL * (E + e)]; rmin = flags[2]; }
    r -= rmin;
    if ((unsigned)r >= (unsigned)N || (unsigned)c >= (unsigned)N) return;
    atomicAdd(&out[((size_t)r << 6) + ch], W[(size_t)ch * N + c]);
}

static inline size_t align256(size_t x) { return (x + 255) & ~(size_t)255; }

extern "C" void kernel_launch(void* const* d_in, const int* in_sizes, int n_in,
                              void* d_out, int out_size, void* d_ws, size_t ws_size,
                              hipStream_t stream) {
    const unsigned int* words = (const unsigned int*)d_in[0];
    const float* W = (const float*)d_in[1];
    const float* b = (const float*)d_in[2];
    float* out = (float*)d_out;

    int E = in_sizes[0] / 2;   // 3,200,000
    int N = in_sizes[1] / 64;  // 100,000
    int total = out_size;      // N*64

    size_t off_flags = 0;
    size_t off_wtb   = align256(off_flags + 256 * sizeof(int));
    size_t off_gtail = align256(off_wtb + (size_t)(N + 1) * 64 * sizeof(unsigned short));
    size_t off_ovf   = align256(off_gtail + (size_t)NBKT * GT_STRIDE * sizeof(int));
    size_t off_recs  = align256(off_ovf + (size_t)OVF_MAX * 2 * sizeof(int));

    int* flags = (int*)((char*)d_ws + off_flags);
    unsigned short* Wtb = (unsigned short*)((char*)d_ws + off_wtb);
    int* gtail = (int*)((char*)d_ws + off_gtail);
    int* ovf   = (int*)((char*)d_ws + off_ovf);
    unsigned int* recs = (unsigned int*)((char*)d_ws + off_recs);

    long long avail = (ws_size > off_recs)
        ? (long long)((ws_size - off_recs) / ((size_t)NBKT * sizeof(int))) : 0;
    int segcap = (int)(avail > 16384 ? 16384 : avail);
    int avg = E / NBKT + 1;
    int nloc = (N + NBKT - 1) >> BSH;
    bool useMain = (nloc <= LROWS_MAX) && (N <= NBKT * LROWS_MAX) && (E > 0) &&
                   (segcap >= avg + avg / 8 + 64);

    if (useMain) {
        // co-residency sizing for cooperative launch (cached queries)
        static int s_maxB = -2;   // -2 = not queried
        static int s_cus = 0;
        if (s_maxB == -2) {
            int mb = 0;
            hipError_t qe = hipOccupancyMaxActiveBlocksPerMultiprocessor(
                &mb, LINK_fused_kernel, 1024, 0);
            s_maxB = (qe == hipSuccess) ? mb : 0;
            int cus = 0;
            int dev = 0;
            (void)hipGetDevice(&dev);
            if (hipDeviceGetAttribute(&cus, hipDeviceAttributeMultiprocessorCount, dev)
                    != hipSuccess || cus <= 0) cus = 256;
            s_cus = cus;
        }
        int grid = s_maxB * s_cus;
        if (grid > NBKT) grid = NBKT;
        if (grid >= 1) {
            void* args[] = { (void*)&words, (void*)&E, (void*)&N, (void*)&W, (void*)&Wtb,
                             (void*)&segcap, (void*)&gtail, (void*)&recs, (void*)&ovf,
                             (void*)&flags, (void*)&b, (void*)&out };
            hipError_t le = hipLaunchCooperativeKernel(
                LINK_fused_kernel, dim3(grid), dim3(1024), args, 0u, stream);
            if (le == hipSuccess) {
                LINK_tail_kernel<<<64, 256, 0, stream>>>(out, b, flags, ovf, Wtb, N);
                return;
            }
        }
        // fall through to fallback on any cooperative-launch failure
    }

    LINK_initout_kernel<<<(total + 255) / 256, 256, 0, stream>>>(out, b, total, flags);
    LINK_analyze_kernel<<<256, 256, 0, stream>>>(words, E, flags);
    long long tthreads = (long long)E * 64;
    LINK_scatter_kernel<<<(int)((tthreads + 255) / 256), 256, 0, stream>>>(
        words, E, W, out, flags, N);
}

// Round 5
// 196.704 us; speedup vs baseline: 2.0282x; 2.0282x over previous
//
#include <hip/hip_runtime.h>

// out[r*64+ch] = b[ch] + sum_{edges (r,c)} W[ch][c],  r normalized by row.min().
// N = 100000, C = 64, E = 3.2M.
//
// R16: un-fuse R15 (cooperative grid.sync form ran 500us at VALUBusy 7.3% /
//  HBM 6% / occ 96% — all-stall: 512-block barrier arrivals serialize on one
//  line + spin; same VALU-seconds as split pipeline smeared over 3x wall).
//  KEEP R15's algorithm as separate dispatches:
//  - 512 low-bit buckets (k=r&511, lr=r>>9): balanced, division-free, 1:1
//    block<->bucket in gather (scan work E, no tail; fixes R13 regression).
//  - part: single end-of-scan flush sweep (~48B runs) — fixes R13's 4x write
//    amplification (WRITE_SIZE 59MB -> expect ~14MB).
//  - vectorized nontemporal edge loads (uint4_ev; builtin needs ext_vector).
//  - bgather: proven R12 dword/half-wave inner loop, SL=56, sentinel pad.
//  Lessons kept: no shfl-broadcast-per-record accum (R3/R7); no same-line
//  global atomics (R5); independent gather loads (R6/R9); no grid.sync (R15).
// ws: flags | Wtb[(N+1)*64 bf16] | gtail[512*16] | ovf | recs[512*segcap]

#define OVF_MAX (1 << 19)
#define NBKT 512
#define BSH 9            // bucket = r & 511, local row = r >> 9
#define SLOTS 30
#define GT_STRIDE 16
#define SL 56            // LDS col-list slots per row
#define LROWS 196        // max local rows: ceil(100352/512)

typedef unsigned int uint2_ev __attribute__((ext_vector_type(2)));
typedef unsigned int uint4_ev __attribute__((ext_vector_type(4)));

__device__ __forceinline__ float bf16u_to_f(unsigned short u) {
    union { unsigned int i; float f; } x; x.i = ((unsigned int)u) << 16; return x.f;
}
__device__ __forceinline__ float bflo(unsigned int u) {
    union { unsigned int i; float f; } x; x.i = u << 16; return x.f;
}
__device__ __forceinline__ float bfhi(unsigned int u) {
    union { unsigned int i; float f; } x; x.i = u & 0xFFFF0000u; return x.f;
}

// 1 block: dtype probe (head+tail odd words) + flags/gtail init.
__global__ __launch_bounds__(1024) void LINK_detect_kernel(
    const unsigned int* __restrict__ words, int E, int* __restrict__ flags,
    int* __restrict__ gtail) {
    long long twoE = 2LL * E;
    int tid = threadIdx.x;
    unsigned int oddOr = 0u;
    int nscan = (int)(twoE < 8192 ? twoE : 8192);
    for (int i = tid; i < nscan; i += blockDim.x) {
        if (i & 1) oddOr |= words[i];
        long long j = twoE - 1 - i;
        if (j >= nscan && (j & 1)) oddOr |= words[j];
    }
    __shared__ unsigned int sred[16];
    for (int off = 32; off > 0; off >>= 1)
        oddOr |= (unsigned int)__shfl_down((int)oddOr, off, 64);
    int wid = tid >> 6;
    if ((tid & 63) == 0) sred[wid] = oddOr;
    __syncthreads();
    if (tid == 0) {
        unsigned int o = 0;
        for (int i = 0; i < (int)(blockDim.x >> 6); ++i) o |= sred[i];
        flags[0] = o ? 1 : 0;    // 1 = int32 layout
        flags[1] = 0x7f7f7f7f;   // rmin "infinity"
        flags[8] = 0;            // ovf count
    }
    for (int k = tid; k < NBKT; k += blockDim.x) gtail[k * GT_STRIDE] = 0;
}

// W [64][N] f32 -> Wtb [N+1][64] bf16 (RNE) via padded LDS tile. Row N = zeros
// (gather sentinel for odd-count padding).
__global__ void LINK_transpose_kernel(const float* __restrict__ W,
                                      unsigned short* __restrict__ Wtb, int N) {
    __shared__ float tile[64][65];
    int n0 = blockIdx.x * 64;
    int lx = threadIdx.x & 63;
    int ly = threadIdx.x >> 6;
#pragma unroll
    for (int it = 0; it < 16; ++it) {
        int ch = ly + 4 * it;
        float v = 0.0f;
        if (n0 + lx < N) v = W[(size_t)ch * N + (n0 + lx)];
        tile[lx][ch] = v;
    }
    __syncthreads();
#pragma unroll
    for (int it = 0; it < 16; ++it) {
        int nn = ly + 4 * it;
        if (n0 + nn <= N) {   // row N gets zeros (load guard) -> sentinel row
            union { float f; unsigned int i; } x; x.f = tile[nn][lx];
            unsigned int u = x.i;
            unsigned int r = (u + 0x7fffu + ((u >> 16) & 1u)) >> 16;  // RNE
            Wtb[((size_t)(n0 + nn) << 6) + lx] = (unsigned short)r;
        }
    }
}

// Edges -> 512 interleaved buckets (k=r&511, rec=(r>>9)<<17|c). LDS-staged,
// single end-of-scan flush sweep of ~12-rec coalesced runs. rmin -> flags[1].
__global__ __launch_bounds__(1024, 8) void LINK_part_kernel(
    const unsigned int* __restrict__ words, int E, int N, int segcap,
    int* __restrict__ gtail, unsigned int* __restrict__ recs,
    int* __restrict__ ovf, int* __restrict__ flags) {
    __shared__ unsigned int lstage[NBKT * SLOTS];  // 60 KB
    __shared__ int lcnt[NBKT];                     // 2 KB
    __shared__ int sred[16];
    int tid = threadIdx.x;
    int lane = tid & 63, wid = tid >> 6;
    for (int k = tid; k < NBKT; k += 1024) lcnt[k] = 0;
    __syncthreads();
    int isInt32 = flags[0];
    int mnr = 0x7f7f7f7f;
    long long P = ((long long)E + 1) >> 1;             // edge pairs
    long long stride = (long long)gridDim.x * 1024;
    for (long long p = (long long)blockIdx.x * 1024 + tid; p < P; p += stride) {
        long long e0 = p << 1;
        int r0, c0, r1 = 0, c1 = 0;
        bool has1 = (e0 + 1 < E);
        if (isInt32) {
            if (has1) {
                uint2_ev rr = __builtin_nontemporal_load((const uint2_ev*)(words + e0));
                uint2_ev cc = __builtin_nontemporal_load((const uint2_ev*)(words + E + e0));
                r0 = (int)rr.x; r1 = (int)rr.y; c0 = (int)cc.x; c1 = (int)cc.y;
            } else {
                r0 = (int)words[e0]; c0 = (int)words[E + e0];
            }
        } else {
            if (has1) {
                uint4_ev rr = __builtin_nontemporal_load((const uint4_ev*)(words + (e0 << 1)));
                uint4_ev cc = __builtin_nontemporal_load((const uint4_ev*)(words + 2LL * E + (e0 << 1)));
                r0 = (int)rr.x; r1 = (int)rr.z; c0 = (int)cc.x; c1 = (int)cc.z;
            } else {
                r0 = (int)words[e0 << 1]; c0 = (int)words[2LL * E + (e0 << 1)];
            }
        }
#pragma unroll
        for (int u = 0; u < 2; ++u) {
            if (u && !has1) break;
            int r = u ? r1 : r0, c = u ? c1 : c0;
            mnr = min(mnr, r);
            if ((unsigned)r < (unsigned)N && (unsigned)c < (unsigned)N) {
                int k = r & (NBKT - 1);
                unsigned int rec = ((unsigned int)(r >> BSH) << 17) | (unsigned int)c;
                int pos = atomicAdd(&lcnt[k], 1);
                if (pos < SLOTS) {
                    lstage[k * SLOTS + pos] = rec;
                } else {  // rare staging overflow: direct global append
                    int g = atomicAdd(&gtail[k * GT_STRIDE], 1);
                    if (g < segcap) recs[(size_t)k * segcap + g] = rec;
                    else {
                        int oi = atomicAdd(&flags[8], 1);
                        if (oi < OVF_MAX) { ovf[2 * oi] = r; ovf[2 * oi + 1] = c; }
                    }
                }
            }
        }
    }
    __syncthreads();
    // single flush sweep: ~12-rec (48B) coalesced runs per bucket
    for (int k = wid; k < NBKT; k += 16) {
        int cnt = lcnt[k]; if (cnt > SLOTS) cnt = SLOTS;
        if (cnt > 0) {
            int g = 0;
            if (lane == 0) g = atomicAdd(&gtail[k * GT_STRIDE], cnt);
            g = __shfl(g, 0);
            if (lane < cnt) {
                int gg = g + lane;
                unsigned int rec = lstage[k * SLOTS + lane];
                if (gg < segcap) recs[(size_t)k * segcap + gg] = rec;
                else {
                    int oi = atomicAdd(&flags[8], 1);
                    if (oi < OVF_MAX) {
                        ovf[2 * oi] = (int)((rec >> 17) << BSH) | k;
                        ovf[2 * oi + 1] = (int)(rec & 0x1FFFF);
                    }
                }
            }
        }
    }
    for (int off = 32; off > 0; off >>= 1) mnr = min(mnr, __shfl_down(mnr, off, 64));
    if (lane == 0) sred[wid] = mnr;
    __syncthreads();
    if (tid == 0) {
        int m = sred[0];
        for (int i = 1; i < 16; ++i) m = min(m, sred[i]);
        atomicMin(&flags[1], m);
    }
}

// One block per bucket (1024 thr, 44.7KB LDS -> 2 blocks/CU, 32 waves/CU,
// grid 512 fully resident). Bin own segment into per-row lists (scan work E
// total), pad odd rows with sentinel col N (Wtb row N = 0), then wave-per-row
// gather: Wtb as uint, lane l of each 32-lane half covers channels 2l/2l+1,
// halves take even/odd records; col indices via ds_read_b128; one
// shfl_xor(32) per row merges halves.
__global__ __launch_bounds__(1024, 8) void LINK_bgather_kernel(
    const int* __restrict__ gtail, const unsigned int* __restrict__ recs, int segcap,
    const unsigned short* __restrict__ Wtb, const float* __restrict__ bias,
    float* __restrict__ out, int* __restrict__ flags, int* __restrict__ ovf, int N) {
    __shared__ __attribute__((aligned(16))) int lcols[LROWS * SL];  // 43.9 KB
    __shared__ int lcnt[LROWS];
    int tid = threadIdx.x;
    int lane = tid & 63, wid = tid >> 6;  // 16 waves
    int nloc = (N + NBKT - 1) >> BSH;
    for (int b = blockIdx.x; b < NBKT; b += gridDim.x) {
        __syncthreads();
        for (int k = tid; k < nloc; k += 1024) lcnt[k] = 0;
        __syncthreads();
        int len = gtail[b * GT_STRIDE]; if (len > segcap) len = segcap;
        const unsigned int* rp = recs + (size_t)b * segcap;
        for (int i = tid; i < len; i += 1024) {
            unsigned int rec = __builtin_nontemporal_load(rp + i);
            int lr = (int)(rec >> 17);
            int c = (int)(rec & 0x1FFFF);
            int pos = atomicAdd(&lcnt[lr], 1);
            if (pos < SL) {
                lcols[lr * SL + pos] = c;
            } else {  // astronomically rare: defer to global ovf cleanup
                int oi = atomicAdd(&flags[8], 1);
                if (oi < OVF_MAX) { ovf[2 * oi] = (lr << BSH) | b; ovf[2 * oi + 1] = c; }
            }
        }
        __syncthreads();
        // Pad odd-count rows to even with sentinel col N (Wtb row N == 0).
        if (tid < nloc) {
            int c0 = lcnt[tid]; if (c0 > SL) c0 = SL;
            if (c0 & 1) { lcols[tid * SL + c0] = N; ++c0; }
            lcnt[tid] = c0;
        }
        __syncthreads();
        int rmin = flags[1];
        int half = lane >> 5, ln = lane & 31;
        const unsigned int* __restrict__ W32 = (const unsigned int*)Wtb;
        float bv = bias[(ln << 1) + half];
        for (int lr = wid; lr < nloc; lr += 16) {
            int cnt = lcnt[lr];         // even, <= SL
            int base = lr * SL;
            float aL = 0.0f, aH = 0.0f;
            int j = 0;
            for (; j + 16 <= cnt; j += 16) {   // 16 recs: 8 dword loads/half
                int4 q0 = *(const int4*)&lcols[base + j + (half << 2)];
                int4 q1 = *(const int4*)&lcols[base + j + 8 + (half << 2)];
                unsigned int u0 = W32[(((unsigned)q0.x) << 5) | ln];
                unsigned int u1 = W32[(((unsigned)q0.y) << 5) | ln];
                unsigned int u2 = W32[(((unsigned)q0.z) << 5) | ln];
                unsigned int u3 = W32[(((unsigned)q0.w) << 5) | ln];
                unsigned int u4 = W32[(((unsigned)q1.x) << 5) | ln];
                unsigned int u5 = W32[(((unsigned)q1.y) << 5) | ln];
                unsigned int u6 = W32[(((unsigned)q1.z) << 5) | ln];
                unsigned int u7 = W32[(((unsigned)q1.w) << 5) | ln];
                float l0 = (bflo(u0) + bflo(u1)) + (bflo(u2) + bflo(u3));
                float l1 = (bflo(u4) + bflo(u5)) + (bflo(u6) + bflo(u7));
                float h0 = (bfhi(u0) + bfhi(u1)) + (bfhi(u2) + bfhi(u3));
                float h1 = (bfhi(u4) + bfhi(u5)) + (bfhi(u6) + bfhi(u7));
                aL += l0 + l1;
                aH += h0 + h1;
            }
            for (; j + 8 <= cnt; j += 8) {
                int4 q = *(const int4*)&lcols[base + j + (half << 2)];
                unsigned int u0 = W32[(((unsigned)q.x) << 5) | ln];
                unsigned int u1 = W32[(((unsigned)q.y) << 5) | ln];
                unsigned int u2 = W32[(((unsigned)q.z) << 5) | ln];
                unsigned int u3 = W32[(((unsigned)q.w) << 5) | ln];
                aL += (bflo(u0) + bflo(u1)) + (bflo(u2) + bflo(u3));
                aH += (bfhi(u0) + bfhi(u1)) + (bfhi(u2) + bfhi(u3));
            }
            for (; j + 4 <= cnt; j += 4) {
                int2 q = *(const int2*)&lcols[base + j + (half << 1)];
                unsigned int u0 = W32[(((unsigned)q.x) << 5) | ln];
                unsigned int u1 = W32[(((unsigned)q.y) << 5) | ln];
                aL += bflo(u0) + bflo(u1);
                aH += bfhi(u0) + bfhi(u1);
            }
            for (; j + 2 <= cnt; j += 2) {
                int c = lcols[base + j + half];
                unsigned int u = W32[(((unsigned)c) << 5) | ln];
                aL += bflo(u);
                aH += bfhi(u);
            }
            aL += __shfl_xor(aL, 32, 64);
            aH += __shfl_xor(aH, 32, 64);
            int orow = (lr << BSH) + b - rmin;
            if ((unsigned)orow < (unsigned)N)
                out[((size_t)orow << 6) + (ln << 1) + half] = (half ? aH : aL) + bv;
        }
    }
}

// Bias for out rows above the bucketed range (rmin large; usually no-op) +
// ovf cleanup (expected zero). Row regions are disjoint -> one kernel.
__global__ void LINK_tail_kernel(float* __restrict__ out, const float* __restrict__ bias,
                                 const int* __restrict__ flags, const int* __restrict__ ovf,
                                 const unsigned short* __restrict__ Wtb, int N) {
    int rmin = flags[1];
    int nloc = (N + NBKT - 1) >> BSH;
    long long start = (long long)nloc * NBKT - (long long)rmin;
    if (start < 0) start = 0;
    if (start < N) {
        long long total = ((long long)N - start) * 64;
        long long base = start * 64;
        long long i0 = (long long)blockIdx.x * blockDim.x + threadIdx.x;
        long long stride = (long long)gridDim.x * blockDim.x;
        for (long long i = i0; i < total; i += stride) out[base + i] = bias[(int)(i & 63)];
    }
    int cnt = flags[8]; if (cnt > OVF_MAX) cnt = OVF_MAX;
    if (cnt == 0) return;
    int g = blockIdx.x * blockDim.x + threadIdx.x;
    int w = g >> 6, lane = g & 63;
    int nw = (gridDim.x * blockDim.x) >> 6;
    for (int i = w; i < cnt; i += nw) {
        int r = ovf[2 * i] - rmin;
        int c = ovf[2 * i + 1];
        if ((unsigned)r >= (unsigned)N || (unsigned)c >= (unsigned)N) continue;
        atomicAdd(&out[((size_t)r << 6) + lane], bf16u_to_f(Wtb[((size_t)c << 6) + lane]));
    }
}

// ---- Fallback path for unexpected shapes/ws ----
__global__ void LINK_initout_kernel(float* __restrict__ out, const float* __restrict__ b,
                                    int total, int* __restrict__ flags) {
    int i = blockIdx.x * blockDim.x + threadIdx.x;
    if (i == 0) { flags[0] = 0; flags[1] = 0x7fffffff; flags[2] = 0x7fffffff; }
    if (i < total) out[i] = b[i & 63];
}

__global__ __launch_bounds__(256) void LINK_analyze_kernel(
    const unsigned int* __restrict__ words, int E, int* __restrict__ flags) {
    const uint4* __restrict__ w4 = (const uint4*)words;
    int tid = blockIdx.x * blockDim.x + threadIdx.x;
    int nth = gridDim.x * blockDim.x;
    int n1 = E >> 2;
    long long twoE = 2LL * E;
    int n2 = (int)(twoE >> 2);
    unsigned int oddOr = 0u;
    int mn32 = 0x7fffffff, mn64 = 0x7fffffff;
    for (int i = tid; i < n2; i += nth) {
        uint4 w = w4[i];
        oddOr |= (w.y | w.w);
        mn64 = min(mn64, min((int)w.x, (int)w.z));
        if (i < n1)
            mn32 = min(mn32, min(min((int)w.x, (int)w.y), min((int)w.z, (int)w.w)));
    }
    for (long long i = ((long long)n1 << 2) + tid; i < E; i += nth)
        mn32 = min(mn32, (int)words[i]);
    for (long long i = ((long long)n2 << 2) + tid; i < twoE; i += nth) {
        unsigned int w = words[i];
        if (i & 1) oddOr |= w; else mn64 = min(mn64, (int)w);
    }
    for (int off = 32; off > 0; off >>= 1) {
        oddOr |= (unsigned int)__shfl_down((int)oddOr, off, 64);
        mn32 = min(mn32, __shfl_down(mn32, off, 64));
        mn64 = min(mn64, __shfl_down(mn64, off, 64));
    }
    __shared__ int s_or[4], s_m32[4], s_m64[4];
    int wid = threadIdx.x >> 6;
    if ((threadIdx.x & 63) == 0) { s_or[wid] = (int)oddOr; s_m32[wid] = mn32; s_m64[wid] = mn64; }
    __syncthreads();
    if (threadIdx.x == 0) {
        int o = s_or[0] | s_or[1] | s_or[2] | s_or[3];
        int a = min(min(s_m32[0], s_m32[1]), min(s_m32[2], s_m32[3]));
        int d = min(min(s_m64[0], s_m64[1]), min(s_m64[2], s_m64[3]));
        if (o) atomicOr(&flags[0], 1);
        atomicMin(&flags[1], a);
        atomicMin(&flags[2], d);
    }
}

__global__ void LINK_scatter_kernel(const unsigned int* __restrict__ words, int E,
                                    const float* __restrict__ W,
                                    float* __restrict__ out,
                                    const int* __restrict__ flags, int N) {
    long long g = (long long)blockIdx.x * blockDim.x + threadIdx.x;
    int e = (int)(g >> 6);
    if (e >= E) return;
    int ch = (int)(g & 63);
    int r, c, rmin;
    if (flags[0]) { r = (int)words[e]; c = (int)words[E + e]; rmin = flags[1]; }
    else { r = (int)words[2LL * e]; c = (int)words[2LL * (E + e)]; rmin = flags[2]; }
    r -= rmin;
    if ((unsigned)r >= (unsigned)N || (unsigned)c >= (unsigned)N) return;
    atomicAdd(&out[((size_t)r << 6) + ch], W[(size_t)ch * N + c]);
}

static inline size_t align256(size_t x) { return (x + 255) & ~(size_t)255; }

extern "C" void kernel_launch(void* const* d_in, const int* in_sizes, int n_in,
                              void* d_out, int out_size, void* d_ws, size_t ws_size,
                              hipStream_t stream) {
    const unsigned int* words = (const unsigned int*)d_in[0];
    const float* W = (const float*)d_in[1];
    const float* b = (const float*)d_in[2];
    float* out = (float*)d_out;

    int E = in_sizes[0] / 2;   // 3,200,000
    int N = in_sizes[1] / 64;  // 100,000
    int total = out_size;      // N*64

    size_t off_flags = 0;
    size_t off_wtb   = align256(off_flags + 256 * sizeof(int));
    size_t off_gtail = align256(off_wtb + (size_t)(N + 1) * 64 * sizeof(unsigned short));
    size_t off_ovf   = align256(off_gtail + (size_t)NBKT * GT_STRIDE * sizeof(int));
    size_t off_recs  = align256(off_ovf + (size_t)OVF_MAX * 2 * sizeof(int));

    int* flags = (int*)((char*)d_ws + off_flags);
    unsigned short* Wtb = (unsigned short*)((char*)d_ws + off_wtb);
    int* gtail = (int*)((char*)d_ws + off_gtail);
    int* ovf   = (int*)((char*)d_ws + off_ovf);
    unsigned int* recs = (unsigned int*)((char*)d_ws + off_recs);

    long long avail = (ws_size > off_recs)
        ? (long long)((ws_size - off_recs) / ((size_t)NBKT * sizeof(int))) : 0;
    int segcap = (int)(avail > 16384 ? 16384 : avail);
    int avg = E / NBKT + 1;
    int nloc = (N + NBKT - 1) >> BSH;
    bool useMain = (nloc <= LROWS) && (E > 0) &&
                   (segcap >= avg + avg / 8 + 64);

    if (useMain) {
        LINK_detect_kernel<<<1, 1024, 0, stream>>>(words, E, flags, gtail);
        LINK_transpose_kernel<<<(N + 64) / 64, 256, 0, stream>>>(W, Wtb, N);
        LINK_part_kernel<<<NBKT, 1024, 0, stream>>>(words, E, N, segcap,
                                                    gtail, recs, ovf, flags);
        LINK_bgather_kernel<<<NBKT, 1024, 0, stream>>>(gtail, recs, segcap, Wtb, b,
                                                       out, flags, ovf, N);
        LINK_tail_kernel<<<64, 256, 0, stream>>>(out, b, flags, ovf, Wtb, N);
    } else {
        LINK_initout_kernel<<<(total + 255) / 256, 256, 0, stream>>>(out, b, total, flags);
        LINK_analyze_kernel<<<256, 256, 0, stream>>>(words, E, flags);
        long long tthreads = (long long)E * 64;
        LINK_scatter_kernel<<<(int)((tthreads + 255) / 256), 256, 0, stream>>>(
            words, E, W, out, flags, N);
    }
}